// Round 1
// baseline (625.305 us; speedup 1.0000x reference)
//
#include <hip/hip_runtime.h>

// ---------------------------------------------------------------------------
// MultiHeadAttention: N=8, S=1024, E=1024, H=16, D=64. External buffers are
// fp32 (detected at runtime by dtype_probe; bf16 also handled).
//
// ROUND 5:
//  * attn rewritten: swapped QK^T (S^T = mfma(K,Q)) makes P lane-local ->
//    PV uses v_mfma_f32_16x16x16_bf16 whose A-fragment layout exactly
//    matches the S^T output layout. NO LDS, NO barriers, NO waitcnt
//    clobbers in the k-loop; compiler free to pipeline global loads.
//  * row-sum: one scalar per lane (q=col), 2 shfl_xor + 4 shfl epilogue.
//  * GEMMs / converts / probe unchanged from round 4.
// ---------------------------------------------------------------------------

typedef unsigned short ushort_t;
typedef __bf16 bf16_8 __attribute__((ext_vector_type(8)));
typedef float f32x4 __attribute__((ext_vector_type(4)));
typedef unsigned short ushort8 __attribute__((ext_vector_type(8)));
typedef short short4v __attribute__((ext_vector_type(4)));

#define SEQ  1024
#define EMB  1024
#define NBAT 8
#define NH   16
#define HD   64
#define MROW (NBAT * SEQ)   // 8192

__device__ __forceinline__ ushort_t cvt_bf16(float x) {
  unsigned u = __float_as_uint(x);
  u += 0x7FFFu + ((u >> 16) & 1u);          // round-nearest-even
  return (ushort_t)(u >> 16);
}
__device__ __forceinline__ float bf2f(ushort_t u) {
  return __uint_as_float(((unsigned)u) << 16);
}
__device__ __forceinline__ short f2bs(float x) {
  return __builtin_bit_cast(short, (__bf16)x);   // native cvt, pairs fuse to v_cvt_pk_bf16_f32
}

// global->LDS direct copy, 16 B/lane. lds base must be wave-uniform; HW
// writes lane i at base + i*16.
__device__ __forceinline__ void async_copy16(const ushort_t* g, ushort_t* l) {
  __builtin_amdgcn_global_load_lds(
      (const __attribute__((address_space(1))) void*)g,
      (__attribute__((address_space(3))) void*)l, 16, 0, 0);
}

// ---------------------------------------------------------------------------
// dtype probe: bf16 view of Wq with many |x|>=4 elements => buffer is fp32.
// ---------------------------------------------------------------------------
__global__ void dtype_probe(const ushort_t* __restrict__ w, int* __restrict__ flag) {
  __shared__ int cnt;
  if (threadIdx.x == 0) cnt = 0;
  __syncthreads();
  int c = 0;
  for (int i = threadIdx.x; i < 4096; i += 256) {
    const int e = (w[i] >> 7) & 0xFF;
    if (e >= 129) ++c;
  }
  atomicAdd(&cnt, c);
  __syncthreads();
  if (threadIdx.x == 0) *flag = (cnt > 256) ? 1 : 0;   // 1 = fp32 buffers
}

__device__ __forceinline__ ushort8 load8(const void* base, size_t off, bool f32) {
  if (f32) {
    const float* p = (const float*)base + off;
    const f32x4 a = *(const f32x4*)p;
    const f32x4 b = *(const f32x4*)(p + 4);
    ushort8 r;
    r[0] = cvt_bf16(a[0]); r[1] = cvt_bf16(a[1]);
    r[2] = cvt_bf16(a[2]); r[3] = cvt_bf16(a[3]);
    r[4] = cvt_bf16(b[0]); r[5] = cvt_bf16(b[1]);
    r[6] = cvt_bf16(b[2]); r[7] = cvt_bf16(b[3]);
    return r;
  }
  return *(const ushort8*)((const ushort_t*)base + off);
}

// convert n8*8 elements (external dtype per flag) to bf16
__global__ __launch_bounds__(256)
void convert_kernel(const void* __restrict__ src, ushort_t* __restrict__ dst,
                    int n8, const int* __restrict__ flag) {
  const int i = blockIdx.x * 256 + threadIdx.x;
  if (i >= n8) return;
  const bool f32 = (*flag != 0);
  *(ushort8*)(dst + (size_t)i * 8) = load8(src, (size_t)i * 8, f32);
}

// ---------------------------------------------------------------------------
// FAST GEMM (pure bf16 A/B): C[m][n] = sum_k A[m][k]*B[n][k] + bias[n]
// 128x128 tile, BK=32, 4 waves 2x2, 4x4 mfma 16x16x32/wave, async staging.
// ---------------------------------------------------------------------------
template <int MODE>   // 0: row-major out; 1: scatter to Vt[n][h][d][s]
__global__ __launch_bounds__(256)
void gemm_async(const ushort_t* __restrict__ A, const ushort_t* __restrict__ B,
                const void* __restrict__ bias, void* __restrict__ Cout,
                const int* __restrict__ flag, int final_out) {
  __shared__ __align__(16) ushort_t As[128 * 32];
  __shared__ __align__(16) ushort_t Bs[128 * 32];
  const bool f32 = (*flag != 0);
  const int tid  = threadIdx.x;
  const int lane = tid & 63;
  const int wave = tid >> 6;
  const int wm = wave & 1, wn = wave >> 1;
  const int col  = lane & 15;
  const int quad = lane >> 4;
  const int bm = (blockIdx.x & 63) << 7;
  const int bn = (blockIdx.x >> 6) << 7;

  const ushort_t* Ab = A + (size_t)bm * EMB;
  const ushort_t* Bb = B + (size_t)bn * EMB;

  float bvv[4];
#pragma unroll
  for (int nt = 0; nt < 4; ++nt) {
    const int i = bn + wn * 64 + nt * 16 + col;
    bvv[nt] = f32 ? ((const float*)bias)[i] : bf2f(((const ushort_t*)bias)[i]);
  }

  f32x4 acc[4][4] = {};

  for (int kb = 0; kb < EMB; kb += 32) {
#pragma unroll
    for (int j = 0; j < 2; ++j) {
      const int s   = j * 256 + tid;       // slot: row=s>>2, 8-elem chunk=s&3
      const int row = s >> 2;
      const int ch  = (s & 3) << 3;
      const int s0  = j * 256 + wave * 64; // wave-uniform LDS base slot
      async_copy16(Ab + (size_t)row * EMB + kb + ch, &As[s0 * 8]);
      async_copy16(Bb + (size_t)row * EMB + kb + ch, &Bs[s0 * 8]);
    }
    __syncthreads();   // drains vmcnt -> async LDS writes visible

    bf16_8 af[4], bfr[4];
#pragma unroll
    for (int mt = 0; mt < 4; ++mt)
      af[mt] = *(const bf16_8*)(As + (wm * 64 + mt * 16 + col) * 32 + quad * 8);
#pragma unroll
    for (int nt = 0; nt < 4; ++nt)
      bfr[nt] = *(const bf16_8*)(Bs + (wn * 64 + nt * 16 + col) * 32 + quad * 8);
#pragma unroll
    for (int mt = 0; mt < 4; ++mt)
#pragma unroll
      for (int nt = 0; nt < 4; ++nt)
        acc[mt][nt] = __builtin_amdgcn_mfma_f32_16x16x32_bf16(af[mt], bfr[nt],
                                                              acc[mt][nt], 0, 0, 0);
    __syncthreads();   // frag reads done before next staging overwrites LDS
  }

#pragma unroll
  for (int mt = 0; mt < 4; ++mt)
#pragma unroll
    for (int nt = 0; nt < 4; ++nt) {
      const int gcol = bn + wn * 64 + nt * 16 + col;
#pragma unroll
      for (int r = 0; r < 4; ++r) {
        const int grow = bm + wm * 64 + mt * 16 + quad * 4 + r;
        const float vv = acc[mt][nt][r] + bvv[nt];
        if (MODE == 0) {
          const size_t idx = (size_t)grow * EMB + gcol;
          if (final_out && f32) ((float*)Cout)[idx] = vv;
          else                  ((ushort_t*)Cout)[idx] = cvt_bf16(vv);
        } else {
          const int nn = grow >> 10, ss = grow & 1023;
          const int hh = gcol >> 6,  dd = gcol & 63;
          ((ushort_t*)Cout)[(size_t)((nn * NH + hh) * HD + dd) * SEQ + ss] =
              cvt_bf16(vv);
        }
      }
    }
}

// ---------------------------------------------------------------------------
// FLEX GEMM (round-3 fallback, external-dtype A/B via runtime flag)
// ---------------------------------------------------------------------------
template <int MODE>
__global__ __launch_bounds__(256)
void gemm_flex(const void* __restrict__ A, const void* __restrict__ B,
               const void* __restrict__ bias, void* __restrict__ Cout,
               const int* __restrict__ flag, int a_ext, int final_out) {
  __shared__ __align__(16) ushort_t As[128 * 32];
  __shared__ __align__(16) ushort_t Bs[128 * 32];
  const bool f32  = (*flag != 0);
  const bool af32 = f32 && (a_ext != 0);
  const int tid  = threadIdx.x;
  const int lane = tid & 63;
  const int wave = tid >> 6;
  const int wm = wave & 1, wn = wave >> 1;
  const int col  = lane & 15;
  const int quad = lane >> 4;
  const int bm = (blockIdx.x & 63) << 7;
  const int bn = (blockIdx.x >> 6) << 7;

  f32x4 acc[4][4] = {};

  for (int kb = 0; kb < EMB; kb += 32) {
    ushort8 ra[2], rb[2];
#pragma unroll
    for (int j = 0; j < 2; ++j) {
      const int s   = j * 256 + tid;
      const int row = s >> 2;
      const int ch  = (s & 3) << 3;
      ra[j] = load8(A, (size_t)(bm + row) * EMB + kb + ch, af32);
      rb[j] = load8(B, (size_t)(bn + row) * EMB + kb + ch, f32);
    }
#pragma unroll
    for (int j = 0; j < 2; ++j) {
      const int s = j * 256 + tid;
      *(ushort8*)(As + s * 8) = ra[j];
      *(ushort8*)(Bs + s * 8) = rb[j];
    }
    __syncthreads();

    bf16_8 af[4], bfr[4];
#pragma unroll
    for (int mt = 0; mt < 4; ++mt)
      af[mt] = *(const bf16_8*)(As + (wm * 64 + mt * 16 + col) * 32 + quad * 8);
#pragma unroll
    for (int nt = 0; nt < 4; ++nt)
      bfr[nt] = *(const bf16_8*)(Bs + (wn * 64 + nt * 16 + col) * 32 + quad * 8);
#pragma unroll
    for (int mt = 0; mt < 4; ++mt)
#pragma unroll
      for (int nt = 0; nt < 4; ++nt)
        acc[mt][nt] = __builtin_amdgcn_mfma_f32_16x16x32_bf16(af[mt], bfr[nt],
                                                              acc[mt][nt], 0, 0, 0);
    __syncthreads();
  }

  float bvv[4];
#pragma unroll
  for (int nt = 0; nt < 4; ++nt) {
    const int i = bn + wn * 64 + nt * 16 + col;
    bvv[nt] = f32 ? ((const float*)bias)[i] : bf2f(((const ushort_t*)bias)[i]);
  }
#pragma unroll
  for (int mt = 0; mt < 4; ++mt)
#pragma unroll
    for (int nt = 0; nt < 4; ++nt) {
      const int gcol = bn + wn * 64 + nt * 16 + col;
#pragma unroll
      for (int r = 0; r < 4; ++r) {
        const int grow = bm + wm * 64 + mt * 16 + quad * 4 + r;
        const float vv = acc[mt][nt][r] + bvv[nt];
        if (MODE == 0) {
          const size_t idx = (size_t)grow * EMB + gcol;
          if (final_out && f32) ((float*)Cout)[idx] = vv;
          else                  ((ushort_t*)Cout)[idx] = cvt_bf16(vv);
        } else {
          const int nn = grow >> 10, ss = grow & 1023;
          const int hh = gcol >> 6,  dd = gcol & 63;
          ((ushort_t*)Cout)[(size_t)((nn * NH + hh) * HD + dd) * SEQ + ss] =
              cvt_bf16(vv);
        }
      }
    }
}

// ---------------------------------------------------------------------------
// Fused flash attention, LDS-free. Each wave: 16 q-rows of one (n,h).
//
// Swapped QK^T: S^T[k][q] = mfma_16x16x32(K_frag, Q_frag). Output layout:
// lane holds S[k = kb + quad*4 + r][q = q0 + col]. That IS the A-operand
// layout of mfma_f32_16x16x16_bf16 (lane holds A[m=lane&15][k=quad*4+j])
// with m=q... wait, m = col = q, k = quad*4+r. So P stays in registers:
// exp2 -> bf16 pack -> PV MFMA. No LDS, no barriers, no waitcnt clobbers.
//
// Softmax with fixed offset M: p = exp2(s_raw*SCL - M); offset cancels in
// the final normalization (exact identity). Per-lane scalar row-sum
// (each lane's p values all belong to q = col); reduced across quads at
// the end with 2 shfl_xor, redistributed to write-rows with 4 shfl.
// O overwrites Q in place (disjoint 16x64 patches per wave).
// ---------------------------------------------------------------------------
__global__ __launch_bounds__(256)
void attn_kernel(const ushort_t* __restrict__ Q, const ushort_t* __restrict__ K,
                 const ushort_t* __restrict__ V, ushort_t* __restrict__ O) {
  const int tid  = threadIdx.x;
  const int lane = tid & 63;
  const int wave = tid >> 6;
  const int col  = lane & 15;
  const int quad = lane >> 4;
  const int gid = blockIdx.x;       // 2048 blocks
  const int qt = gid & 15;
  const int nh = gid >> 4;
  const int h  = nh & 15;
  const int n  = nh >> 4;
  const int q0 = qt * 64 + wave * 16;

  const ushort_t* qp = Q + (size_t)(n * SEQ + q0 + col) * EMB + h * HD + quad * 8;
  const bf16_8 aq0 = *(const bf16_8*)qp;          // d 0..31 (B-operand of S^T)
  const bf16_8 aq1 = *(const bf16_8*)(qp + 32);   // d 32..63

  const ushort_t* kp = K + (size_t)(n * SEQ + col) * EMB + h * HD + quad * 8;
  const ushort_t* vp = V + (size_t)(nh * HD + col) * SEQ + quad * 4;

  f32x4 acc[4] = {};
  float lsum = 0.f;                 // partial row-sum for q = q0 + col

  const float SCL = 0.04508422f;    // log2(e)/sqrt(1024)
  const float MOF = 16.0f;          // fixed softmax offset (cancels exactly)

  for (int kb = 0; kb < SEQ; kb += 32) {
    const f32x4 z = {};
    const ushort_t* kpi = kp + (size_t)kb * EMB;
    const ushort_t* vpi = vp + kb;
    // K fragments: lane holds K[kb(+16) + col][d = quad*8 .. +7]
    const bf16_8 bk00 = *(const bf16_8*)(kpi);
    const bf16_8 bk01 = *(const bf16_8*)(kpi + 32);
    const bf16_8 bk10 = *(const bf16_8*)(kpi + 16 * EMB);
    const bf16_8 bk11 = *(const bf16_8*)(kpi + 16 * EMB + 32);
    // V fragments for the K=16 PV mfma: lane holds V[kb(+16)+quad*4+j][dt*16+col]
    short4v bv0[4], bv1[4];
#pragma unroll
    for (int dt = 0; dt < 4; ++dt) {
      bv0[dt] = *(const short4v*)(vpi + (size_t)dt * 16 * SEQ);
      bv1[dt] = *(const short4v*)(vpi + (size_t)dt * 16 * SEQ + 16);
    }

    // S^T = K · Q^T : s0[r] = S[kb+quad*4+r][q0+col], s1 = +16 k-block
    f32x4 s0 = __builtin_amdgcn_mfma_f32_16x16x32_bf16(bk00, aq0, z, 0, 0, 0);
    s0 = __builtin_amdgcn_mfma_f32_16x16x32_bf16(bk01, aq1, s0, 0, 0, 0);
    f32x4 s1 = __builtin_amdgcn_mfma_f32_16x16x32_bf16(bk10, aq0, z, 0, 0, 0);
    s1 = __builtin_amdgcn_mfma_f32_16x16x32_bf16(bk11, aq1, s1, 0, 0, 0);

    short4v pa0, pa1;
#pragma unroll
    for (int r = 0; r < 4; ++r) {
      const float p0 = exp2f(__builtin_fmaf(s0[r], SCL, -MOF));
      const float p1 = exp2f(__builtin_fmaf(s1[r], SCL, -MOF));
      lsum += p0 + p1;
      pa0[r] = f2bs(p0);
      pa1[r] = f2bs(p1);
    }

    // PV: pa0/pa1 are exact A-fragments (P[q=col][k=quad*4+j]) for K=16 mfma
#pragma unroll
    for (int dt = 0; dt < 4; ++dt) {
      acc[dt] = __builtin_amdgcn_mfma_f32_16x16x16bf16_1k(pa0, bv0[dt], acc[dt], 0, 0, 0);
      acc[dt] = __builtin_amdgcn_mfma_f32_16x16x16bf16_1k(pa1, bv1[dt], acc[dt], 0, 0, 0);
    }
  }

  // reduce row-sums across the 4 quads (lanes col, col+16, col+32, col+48
  // together hold all k for q = col)
  float tot = lsum;
  tot += __shfl_xor(tot, 16, 64);
  tot += __shfl_xor(tot, 32, 64);
  // redistribute: write-rows of this lane are q = quad*4 + r; the total for
  // that q lives in the lane of the same 16-group with col = quad*4 + r
  float rinv[4];
#pragma unroll
  for (int r = 0; r < 4; ++r)
    rinv[r] = 1.0f / __shfl(tot, quad * 4 + r, 16);

#pragma unroll
  for (int dt = 0; dt < 4; ++dt)
#pragma unroll
    for (int r = 0; r < 4; ++r)
      O[(size_t)(n * SEQ + q0 + quad * 4 + r) * EMB + h * HD + dt * 16 + col] =
          cvt_bf16(acc[dt][r] * rinv[r]);
}

// ---------------------------------------------------------------------------
extern "C" void kernel_launch(void* const* d_in, const int* in_sizes, int n_in,
                              void* d_out, int out_size, void* d_ws, size_t ws_size,
                              hipStream_t stream) {
  const void* q  = d_in[0];
  const void* k  = d_in[1];
  const void* v  = d_in[2];
  const void* Wq = d_in[3];
  const void* bq = d_in[4];
  const void* Wk = d_in[5];
  const void* bk = d_in[6];
  const void* Wv = d_in[7];
  const void* bv = d_in[8];
  const void* Wo = d_in[9];
  const void* bo = d_in[10];

  const size_t TE = (size_t)MROW * EMB;   // 8.39M elems
  const size_t WE = (size_t)EMB * EMB;    // 1.05M elems
  int* flag = (int*)d_ws;
  char* base = (char*)d_ws + 256;
  const size_t NEED = 256 + (4 * TE + 4 * WE) * sizeof(ushort_t);

  const dim3 tB(256);
  dtype_probe<<<dim3(1), tB, 0, stream>>>((const ushort_t*)Wq, flag);

  if (ws_size >= NEED) {
    // fast path: convert everything to bf16, async GEMMs
    ushort_t* cq  = (ushort_t*)base;            // becomes Vt after gemm Q
    ushort_t* ck  = cq + TE;
    ushort_t* cv  = ck + TE;
    ushort_t* Qp  = cv + TE;                    // becomes O after attn
    ushort_t* cWq = Qp + TE;
    ushort_t* cWk = cWq + WE;
    ushort_t* cWv = cWk + WE;
    ushort_t* cWo = cWv + WE;
    ushort_t* Kp  = (ushort_t*)d_out;           // K staged in d_out (dead later)
    ushort_t* Vt  = cq;
    ushort_t* Oa  = Qp;

    const int n8t = (int)(TE / 8), n8w = (int)(WE / 8);
    convert_kernel<<<dim3(n8t / 256), tB, 0, stream>>>(q,  cq,  n8t, flag);
    convert_kernel<<<dim3(n8t / 256), tB, 0, stream>>>(k,  ck,  n8t, flag);
    convert_kernel<<<dim3(n8t / 256), tB, 0, stream>>>(v,  cv,  n8t, flag);
    convert_kernel<<<dim3(n8w / 256), tB, 0, stream>>>(Wq, cWq, n8w, flag);
    convert_kernel<<<dim3(n8w / 256), tB, 0, stream>>>(Wk, cWk, n8w, flag);
    convert_kernel<<<dim3(n8w / 256), tB, 0, stream>>>(Wv, cWv, n8w, flag);
    convert_kernel<<<dim3(n8w / 256), tB, 0, stream>>>(Wo, cWo, n8w, flag);

    const dim3 gB(512);
    gemm_async<0><<<gB, tB, 0, stream>>>(cq, cWq, bq, Qp, flag, 0);
    gemm_async<0><<<gB, tB, 0, stream>>>(ck, cWk, bk, Kp, flag, 0);
    gemm_async<1><<<gB, tB, 0, stream>>>(cv, cWv, bv, Vt, flag, 0);  // cq dead
    attn_kernel<<<dim3(2048), tB, 0, stream>>>(Qp, Kp, Vt, Oa);
    gemm_async<0><<<gB, tB, 0, stream>>>(Oa, cWo, bo, d_out, flag, 1);
  } else {
    // fallback: round-3 structure (on-the-fly dtype, register staging)
    ushort_t* Qp = (ushort_t*)base;
    ushort_t* Vt = Qp + TE;
    ushort_t* Kp = (ushort_t*)d_out;
    ushort_t* Oa = Qp;
    const dim3 gB(512);
    gemm_flex<0><<<gB, tB, 0, stream>>>(q, Wq, bq, Qp, flag, 1, 0);
    gemm_flex<0><<<gB, tB, 0, stream>>>(k, Wk, bk, Kp, flag, 1, 0);
    gemm_flex<1><<<gB, tB, 0, stream>>>(v, Wv, bv, Vt, flag, 1, 0);
    attn_kernel<<<dim3(2048), tB, 0, stream>>>(Qp, Kp, Vt, Oa);
    gemm_flex<0><<<gB, tB, 0, stream>>>(Oa, Wo, bo, d_out, flag, 0, 1);
  }
}

// Round 2
// 404.420 us; speedup vs baseline: 1.5462x; 1.5462x over previous
//
#include <hip/hip_runtime.h>

// ---------------------------------------------------------------------------
// MultiHeadAttention: N=8, S=1024, E=1024, H=16, D=64. External buffers are
// fp32 (detected at runtime by dtype_probe; bf16 also handled).
//
// ROUND 6:
//  * attn: explicit 2-deep register double-buffer (issue next tile's K/V
//    loads before computing current tile) -> loads stay in flight across
//    the compute phase instead of exposing L2 latency every iteration.
//  * 32 q-rows per wave (2 q-groups): halves per-FLOP K/V traffic, 4
//    independent QK chains for ILP. Grid 2048 -> 1024 blocks.
//  * Vt stored k-interleaved (within each 32-chunk: pos = quad*8+half*4+r)
//    so one 16B load feeds both K=16 PV mfmas -> V loads 8x8B -> 4x16B.
//  * XCD-affinity swizzle: nh = gid & 127 (all 8 q-blocks of an (n,h)
//    land on the same XCD's L2 under %8 round-robin dispatch).
//  * GEMMs / converts / probe unchanged except the MODE-1 Vt scatter perm.
// ---------------------------------------------------------------------------

typedef unsigned short ushort_t;
typedef __bf16 bf16_8 __attribute__((ext_vector_type(8)));
typedef float f32x4 __attribute__((ext_vector_type(4)));
typedef unsigned short ushort8 __attribute__((ext_vector_type(8)));
typedef short short4v __attribute__((ext_vector_type(4)));
typedef short short8v __attribute__((ext_vector_type(8)));

#define SEQ  1024
#define EMB  1024
#define NBAT 8
#define NH   16
#define HD   64
#define MROW (NBAT * SEQ)   // 8192

__device__ __forceinline__ ushort_t cvt_bf16(float x) {
  unsigned u = __float_as_uint(x);
  u += 0x7FFFu + ((u >> 16) & 1u);          // round-nearest-even
  return (ushort_t)(u >> 16);
}
__device__ __forceinline__ float bf2f(ushort_t u) {
  return __uint_as_float(((unsigned)u) << 16);
}
__device__ __forceinline__ short f2bs(float x) {
  return __builtin_bit_cast(short, (__bf16)x);   // native cvt, pairs fuse to v_cvt_pk_bf16_f32
}

// global->LDS direct copy, 16 B/lane. lds base must be wave-uniform; HW
// writes lane i at base + i*16.
__device__ __forceinline__ void async_copy16(const ushort_t* g, ushort_t* l) {
  __builtin_amdgcn_global_load_lds(
      (const __attribute__((address_space(1))) void*)g,
      (__attribute__((address_space(3))) void*)l, 16, 0, 0);
}

// Vt k-interleave: within each 32-element chunk of s, element kl goes to
// position quad(kl)*8 + half(kl)*4 + r(kl). attn then reads 16B per lane
// covering {half0: quad*4+r} ++ {half1: quad*4+r} = both K=16 PV fragments.
__device__ __forceinline__ int vt_perm(int ss) {
  const int kl = ss & 31;
  return (ss & ~31) | (((kl & 15) >> 2) << 3) | ((kl >> 4) << 2) | (kl & 3);
}

// ---------------------------------------------------------------------------
// dtype probe: bf16 view of Wq with many |x|>=4 elements => buffer is fp32.
// ---------------------------------------------------------------------------
__global__ void dtype_probe(const ushort_t* __restrict__ w, int* __restrict__ flag) {
  __shared__ int cnt;
  if (threadIdx.x == 0) cnt = 0;
  __syncthreads();
  int c = 0;
  for (int i = threadIdx.x; i < 4096; i += 256) {
    const int e = (w[i] >> 7) & 0xFF;
    if (e >= 129) ++c;
  }
  atomicAdd(&cnt, c);
  __syncthreads();
  if (threadIdx.x == 0) *flag = (cnt > 256) ? 1 : 0;   // 1 = fp32 buffers
}

__device__ __forceinline__ ushort8 load8(const void* base, size_t off, bool f32) {
  if (f32) {
    const float* p = (const float*)base + off;
    const f32x4 a = *(const f32x4*)p;
    const f32x4 b = *(const f32x4*)(p + 4);
    ushort8 r;
    r[0] = cvt_bf16(a[0]); r[1] = cvt_bf16(a[1]);
    r[2] = cvt_bf16(a[2]); r[3] = cvt_bf16(a[3]);
    r[4] = cvt_bf16(b[0]); r[5] = cvt_bf16(b[1]);
    r[6] = cvt_bf16(b[2]); r[7] = cvt_bf16(b[3]);
    return r;
  }
  return *(const ushort8*)((const ushort_t*)base + off);
}

// convert n8*8 elements (external dtype per flag) to bf16
__global__ __launch_bounds__(256)
void convert_kernel(const void* __restrict__ src, ushort_t* __restrict__ dst,
                    int n8, const int* __restrict__ flag) {
  const int i = blockIdx.x * 256 + threadIdx.x;
  if (i >= n8) return;
  const bool f32 = (*flag != 0);
  *(ushort8*)(dst + (size_t)i * 8) = load8(src, (size_t)i * 8, f32);
}

// ---------------------------------------------------------------------------
// FAST GEMM (pure bf16 A/B): C[m][n] = sum_k A[m][k]*B[n][k] + bias[n]
// 128x128 tile, BK=32, 4 waves 2x2, 4x4 mfma 16x16x32/wave, async staging.
// ---------------------------------------------------------------------------
template <int MODE>   // 0: row-major out; 1: scatter to Vt[n][h][d][perm(s)]
__global__ __launch_bounds__(256)
void gemm_async(const ushort_t* __restrict__ A, const ushort_t* __restrict__ B,
                const void* __restrict__ bias, void* __restrict__ Cout,
                const int* __restrict__ flag, int final_out) {
  __shared__ __align__(16) ushort_t As[128 * 32];
  __shared__ __align__(16) ushort_t Bs[128 * 32];
  const bool f32 = (*flag != 0);
  const int tid  = threadIdx.x;
  const int lane = tid & 63;
  const int wave = tid >> 6;
  const int wm = wave & 1, wn = wave >> 1;
  const int col  = lane & 15;
  const int quad = lane >> 4;
  const int bm = (blockIdx.x & 63) << 7;
  const int bn = (blockIdx.x >> 6) << 7;

  const ushort_t* Ab = A + (size_t)bm * EMB;
  const ushort_t* Bb = B + (size_t)bn * EMB;

  float bvv[4];
#pragma unroll
  for (int nt = 0; nt < 4; ++nt) {
    const int i = bn + wn * 64 + nt * 16 + col;
    bvv[nt] = f32 ? ((const float*)bias)[i] : bf2f(((const ushort_t*)bias)[i]);
  }

  f32x4 acc[4][4] = {};

  for (int kb = 0; kb < EMB; kb += 32) {
#pragma unroll
    for (int j = 0; j < 2; ++j) {
      const int s   = j * 256 + tid;       // slot: row=s>>2, 8-elem chunk=s&3
      const int row = s >> 2;
      const int ch  = (s & 3) << 3;
      const int s0  = j * 256 + wave * 64; // wave-uniform LDS base slot
      async_copy16(Ab + (size_t)row * EMB + kb + ch, &As[s0 * 8]);
      async_copy16(Bb + (size_t)row * EMB + kb + ch, &Bs[s0 * 8]);
    }
    __syncthreads();   // drains vmcnt -> async LDS writes visible

    bf16_8 af[4], bfr[4];
#pragma unroll
    for (int mt = 0; mt < 4; ++mt)
      af[mt] = *(const bf16_8*)(As + (wm * 64 + mt * 16 + col) * 32 + quad * 8);
#pragma unroll
    for (int nt = 0; nt < 4; ++nt)
      bfr[nt] = *(const bf16_8*)(Bs + (wn * 64 + nt * 16 + col) * 32 + quad * 8);
#pragma unroll
    for (int mt = 0; mt < 4; ++mt)
#pragma unroll
      for (int nt = 0; nt < 4; ++nt)
        acc[mt][nt] = __builtin_amdgcn_mfma_f32_16x16x32_bf16(af[mt], bfr[nt],
                                                              acc[mt][nt], 0, 0, 0);
    __syncthreads();   // frag reads done before next staging overwrites LDS
  }

#pragma unroll
  for (int mt = 0; mt < 4; ++mt)
#pragma unroll
    for (int nt = 0; nt < 4; ++nt) {
      const int gcol = bn + wn * 64 + nt * 16 + col;
#pragma unroll
      for (int r = 0; r < 4; ++r) {
        const int grow = bm + wm * 64 + mt * 16 + quad * 4 + r;
        const float vv = acc[mt][nt][r] + bvv[nt];
        if (MODE == 0) {
          const size_t idx = (size_t)grow * EMB + gcol;
          if (final_out && f32) ((float*)Cout)[idx] = vv;
          else                  ((ushort_t*)Cout)[idx] = cvt_bf16(vv);
        } else {
          const int nn = grow >> 10, ss = grow & 1023;
          const int hh = gcol >> 6,  dd = gcol & 63;
          ((ushort_t*)Cout)[(size_t)((nn * NH + hh) * HD + dd) * SEQ + vt_perm(ss)] =
              cvt_bf16(vv);
        }
      }
    }
}

// ---------------------------------------------------------------------------
// FLEX GEMM (round-3 fallback, external-dtype A/B via runtime flag)
// ---------------------------------------------------------------------------
template <int MODE>
__global__ __launch_bounds__(256)
void gemm_flex(const void* __restrict__ A, const void* __restrict__ B,
               const void* __restrict__ bias, void* __restrict__ Cout,
               const int* __restrict__ flag, int a_ext, int final_out) {
  __shared__ __align__(16) ushort_t As[128 * 32];
  __shared__ __align__(16) ushort_t Bs[128 * 32];
  const bool f32  = (*flag != 0);
  const bool af32 = f32 && (a_ext != 0);
  const int tid  = threadIdx.x;
  const int lane = tid & 63;
  const int wave = tid >> 6;
  const int wm = wave & 1, wn = wave >> 1;
  const int col  = lane & 15;
  const int quad = lane >> 4;
  const int bm = (blockIdx.x & 63) << 7;
  const int bn = (blockIdx.x >> 6) << 7;

  f32x4 acc[4][4] = {};

  for (int kb = 0; kb < EMB; kb += 32) {
    ushort8 ra[2], rb[2];
#pragma unroll
    for (int j = 0; j < 2; ++j) {
      const int s   = j * 256 + tid;
      const int row = s >> 2;
      const int ch  = (s & 3) << 3;
      ra[j] = load8(A, (size_t)(bm + row) * EMB + kb + ch, af32);
      rb[j] = load8(B, (size_t)(bn + row) * EMB + kb + ch, f32);
    }
#pragma unroll
    for (int j = 0; j < 2; ++j) {
      const int s = j * 256 + tid;
      *(ushort8*)(As + s * 8) = ra[j];
      *(ushort8*)(Bs + s * 8) = rb[j];
    }
    __syncthreads();

    bf16_8 af[4], bfr[4];
#pragma unroll
    for (int mt = 0; mt < 4; ++mt)
      af[mt] = *(const bf16_8*)(As + (wm * 64 + mt * 16 + col) * 32 + quad * 8);
#pragma unroll
    for (int nt = 0; nt < 4; ++nt)
      bfr[nt] = *(const bf16_8*)(Bs + (wn * 64 + nt * 16 + col) * 32 + quad * 8);
#pragma unroll
    for (int mt = 0; mt < 4; ++mt)
#pragma unroll
      for (int nt = 0; nt < 4; ++nt)
        acc[mt][nt] = __builtin_amdgcn_mfma_f32_16x16x32_bf16(af[mt], bfr[nt],
                                                              acc[mt][nt], 0, 0, 0);
    __syncthreads();
  }

  float bvv[4];
#pragma unroll
  for (int nt = 0; nt < 4; ++nt) {
    const int i = bn + wn * 64 + nt * 16 + col;
    bvv[nt] = f32 ? ((const float*)bias)[i] : bf2f(((const ushort_t*)bias)[i]);
  }
#pragma unroll
  for (int mt = 0; mt < 4; ++mt)
#pragma unroll
    for (int nt = 0; nt < 4; ++nt) {
      const int gcol = bn + wn * 64 + nt * 16 + col;
#pragma unroll
      for (int r = 0; r < 4; ++r) {
        const int grow = bm + wm * 64 + mt * 16 + quad * 4 + r;
        const float vv = acc[mt][nt][r] + bvv[nt];
        if (MODE == 0) {
          const size_t idx = (size_t)grow * EMB + gcol;
          if (final_out && f32) ((float*)Cout)[idx] = vv;
          else                  ((ushort_t*)Cout)[idx] = cvt_bf16(vv);
        } else {
          const int nn = grow >> 10, ss = grow & 1023;
          const int hh = gcol >> 6,  dd = gcol & 63;
          ((ushort_t*)Cout)[(size_t)((nn * NH + hh) * HD + dd) * SEQ + vt_perm(ss)] =
              cvt_bf16(vv);
        }
      }
    }
}

// ---------------------------------------------------------------------------
// Fused flash attention, LDS-free, register double-buffered.
// Each wave: 32 q-rows (2 groups of 16) of one (n,h). Block = 4 waves =
// 128 q-rows; grid = 8 q-blocks x 128 (n,h) = 1024 blocks.
//
// Swapped QK^T: S^T = mfma_16x16x32(K_frag, Q_frag); lane holds
// S[k=kb+quad*4+r][q=q0+col] == the A-fragment of mfma_f32_16x16x16_bf16.
// P: exp2 -> bf16 in registers -> PV. No LDS, no barriers.
//
// K/V tile loads are double-buffered in registers: next tile's 8 loads are
// issued BEFORE the current tile's compute, so the compiler's vmcnt wait
// for the current regs leaves the next loads in flight (T14/T4 pattern).
//
// Vt is k-interleaved (see vt_perm) so one 16B load per dt supplies both
// K=16 PV fragments (halves of the 32-k tile).
// ---------------------------------------------------------------------------
__global__ __launch_bounds__(256)
void attn_kernel(const ushort_t* __restrict__ Q, const ushort_t* __restrict__ K,
                 const ushort_t* __restrict__ V, ushort_t* __restrict__ O) {
  const int tid  = threadIdx.x;
  const int lane = tid & 63;
  const int wave = tid >> 6;
  const int col  = lane & 15;
  const int quad = lane >> 4;
  const int gid = blockIdx.x;       // 1024 blocks
  const int nh  = gid & 127;        // blocks sharing (n,h) are 128 apart -> same XCD
  const int qb  = gid >> 7;
  const int h  = nh & 15;
  const int n  = nh >> 4;
  const int q0 = qb * 128 + wave * 32;

  // Q fragments for 2 q-groups (rows q0+g*16+col), d 0..31 / 32..63
  bf16_8 aq0[2], aq1[2];
#pragma unroll
  for (int g = 0; g < 2; ++g) {
    const ushort_t* qp =
        Q + (size_t)(n * SEQ + q0 + g * 16 + col) * EMB + h * HD + quad * 8;
    aq0[g] = *(const bf16_8*)qp;
    aq1[g] = *(const bf16_8*)(qp + 32);
  }

  const ushort_t* kp  = K + (size_t)(n * SEQ + col) * EMB + h * HD + quad * 8;
  const ushort_t* vpb = V + ((size_t)nh * HD + col) * SEQ + quad * 8;

  f32x4 acc[2][4] = {};
  float lsum[2] = {0.f, 0.f};

  const float SCL = 0.04508422f;    // log2(e)/sqrt(1024)
  const float MOF = 16.0f;          // fixed softmax offset (cancels exactly)

#define ATTN_LOAD(KX, VX, KB_)                                               \
  do {                                                                       \
    const ushort_t* kpi = kp + (size_t)(KB_) * EMB;                          \
    KX[0] = *(const bf16_8*)(kpi);                                           \
    KX[1] = *(const bf16_8*)(kpi + 32);                                      \
    KX[2] = *(const bf16_8*)(kpi + 16 * EMB);                                \
    KX[3] = *(const bf16_8*)(kpi + 16 * EMB + 32);                           \
    _Pragma("unroll")                                                        \
    for (int dt = 0; dt < 4; ++dt)                                           \
      VX[dt] = *(const short8v*)(vpb + (size_t)dt * 16 * SEQ + (KB_));       \
  } while (0)

#define ATTN_TILE(KX, VX)                                                    \
  do {                                                                       \
    _Pragma("unroll")                                                        \
    for (int g = 0; g < 2; ++g) {                                            \
      const f32x4 z = {};                                                    \
      f32x4 s0 = __builtin_amdgcn_mfma_f32_16x16x32_bf16(KX[0], aq0[g], z, 0, 0, 0); \
      s0 = __builtin_amdgcn_mfma_f32_16x16x32_bf16(KX[1], aq1[g], s0, 0, 0, 0);      \
      f32x4 s1 = __builtin_amdgcn_mfma_f32_16x16x32_bf16(KX[2], aq0[g], z, 0, 0, 0); \
      s1 = __builtin_amdgcn_mfma_f32_16x16x32_bf16(KX[3], aq1[g], s1, 0, 0, 0);      \
      short4v pa0, pa1;                                                      \
      _Pragma("unroll")                                                      \
      for (int r = 0; r < 4; ++r) {                                          \
        const float p0 = exp2f(__builtin_fmaf(s0[r], SCL, -MOF));            \
        const float p1 = exp2f(__builtin_fmaf(s1[r], SCL, -MOF));            \
        lsum[g] += p0 + p1;                                                  \
        pa0[r] = f2bs(p0);                                                   \
        pa1[r] = f2bs(p1);                                                   \
      }                                                                      \
      _Pragma("unroll")                                                      \
      for (int dt = 0; dt < 4; ++dt) {                                       \
        const short4v lo = __builtin_shufflevector(VX[dt], VX[dt], 0, 1, 2, 3); \
        const short4v hi = __builtin_shufflevector(VX[dt], VX[dt], 4, 5, 6, 7); \
        acc[g][dt] = __builtin_amdgcn_mfma_f32_16x16x16bf16_1k(pa0, lo, acc[g][dt], 0, 0, 0); \
        acc[g][dt] = __builtin_amdgcn_mfma_f32_16x16x16bf16_1k(pa1, hi, acc[g][dt], 0, 0, 0); \
      }                                                                      \
    }                                                                        \
  } while (0)

  bf16_8 KA[4], KB2[4];
  short8v VA[4], VB[4];

  ATTN_LOAD(KA, VA, 0);
  for (int kb = 0; kb < SEQ; kb += 64) {
    ATTN_LOAD(KB2, VB, kb + 32);       // issue next loads BEFORE current compute
    ATTN_TILE(KA, VA);
    if (kb + 64 < SEQ) ATTN_LOAD(KA, VA, kb + 64);
    ATTN_TILE(KB2, VB);
  }

#undef ATTN_LOAD
#undef ATTN_TILE

  // per-group row-sum reduction and output
#pragma unroll
  for (int g = 0; g < 2; ++g) {
    float tot = lsum[g];
    tot += __shfl_xor(tot, 16, 64);
    tot += __shfl_xor(tot, 32, 64);
    float rinv[4];
#pragma unroll
    for (int r = 0; r < 4; ++r)
      rinv[r] = 1.0f / __shfl(tot, quad * 4 + r, 16);
#pragma unroll
    for (int dt = 0; dt < 4; ++dt)
#pragma unroll
      for (int r = 0; r < 4; ++r)
        O[(size_t)(n * SEQ + q0 + g * 16 + quad * 4 + r) * EMB + h * HD +
          dt * 16 + col] = cvt_bf16(acc[g][dt][r] * rinv[r]);
  }
}

// ---------------------------------------------------------------------------
extern "C" void kernel_launch(void* const* d_in, const int* in_sizes, int n_in,
                              void* d_out, int out_size, void* d_ws, size_t ws_size,
                              hipStream_t stream) {
  const void* q  = d_in[0];
  const void* k  = d_in[1];
  const void* v  = d_in[2];
  const void* Wq = d_in[3];
  const void* bq = d_in[4];
  const void* Wk = d_in[5];
  const void* bk = d_in[6];
  const void* Wv = d_in[7];
  const void* bv = d_in[8];
  const void* Wo = d_in[9];
  const void* bo = d_in[10];

  const size_t TE = (size_t)MROW * EMB;   // 8.39M elems
  const size_t WE = (size_t)EMB * EMB;    // 1.05M elems
  int* flag = (int*)d_ws;
  char* base = (char*)d_ws + 256;
  const size_t NEED = 256 + (4 * TE + 4 * WE) * sizeof(ushort_t);

  const dim3 tB(256);
  dtype_probe<<<dim3(1), tB, 0, stream>>>((const ushort_t*)Wq, flag);

  if (ws_size >= NEED) {
    // fast path: convert everything to bf16, async GEMMs
    ushort_t* cq  = (ushort_t*)base;            // becomes Vt after gemm Q
    ushort_t* ck  = cq + TE;
    ushort_t* cv  = ck + TE;
    ushort_t* Qp  = cv + TE;                    // becomes O after attn
    ushort_t* cWq = Qp + TE;
    ushort_t* cWk = cWq + WE;
    ushort_t* cWv = cWk + WE;
    ushort_t* cWo = cWv + WE;
    ushort_t* Kp  = (ushort_t*)d_out;           // K staged in d_out (dead later)
    ushort_t* Vt  = cq;
    ushort_t* Oa  = Qp;

    const int n8t = (int)(TE / 8), n8w = (int)(WE / 8);
    convert_kernel<<<dim3(n8t / 256), tB, 0, stream>>>(q,  cq,  n8t, flag);
    convert_kernel<<<dim3(n8t / 256), tB, 0, stream>>>(k,  ck,  n8t, flag);
    convert_kernel<<<dim3(n8t / 256), tB, 0, stream>>>(v,  cv,  n8t, flag);
    convert_kernel<<<dim3(n8w / 256), tB, 0, stream>>>(Wq, cWq, n8w, flag);
    convert_kernel<<<dim3(n8w / 256), tB, 0, stream>>>(Wk, cWk, n8w, flag);
    convert_kernel<<<dim3(n8w / 256), tB, 0, stream>>>(Wv, cWv, n8w, flag);
    convert_kernel<<<dim3(n8w / 256), tB, 0, stream>>>(Wo, cWo, n8w, flag);

    const dim3 gB(512);
    gemm_async<0><<<gB, tB, 0, stream>>>(cq, cWq, bq, Qp, flag, 0);
    gemm_async<0><<<gB, tB, 0, stream>>>(ck, cWk, bk, Kp, flag, 0);
    gemm_async<1><<<gB, tB, 0, stream>>>(cv, cWv, bv, Vt, flag, 0);  // cq dead
    attn_kernel<<<dim3(1024), tB, 0, stream>>>(Qp, Kp, Vt, Oa);
    gemm_async<0><<<gB, tB, 0, stream>>>(Oa, cWo, bo, d_out, flag, 1);
  } else {
    // fallback: round-3 structure (on-the-fly dtype, register staging)
    ushort_t* Qp = (ushort_t*)base;
    ushort_t* Vt = Qp + TE;
    ushort_t* Kp = (ushort_t*)d_out;
    ushort_t* Oa = Qp;
    const dim3 gB(512);
    gemm_flex<0><<<gB, tB, 0, stream>>>(q, Wq, bq, Qp, flag, 1, 0);
    gemm_flex<0><<<gB, tB, 0, stream>>>(k, Wk, bk, Kp, flag, 1, 0);
    gemm_flex<1><<<gB, tB, 0, stream>>>(v, Wv, bv, Vt, flag, 1, 0);
    attn_kernel<<<dim3(1024), tB, 0, stream>>>(Qp, Kp, Vt, Oa);
    gemm_flex<0><<<gB, tB, 0, stream>>>(Oa, Wo, bo, d_out, flag, 0, 1);
  }
}

// Round 3
// 398.241 us; speedup vs baseline: 1.5702x; 1.0155x over previous
//
#include <hip/hip_runtime.h>

// ---------------------------------------------------------------------------
// MultiHeadAttention: N=8, S=1024, E=1024, H=16, D=64. External buffers are
// fp32 (detected at runtime by dtype_probe; bf16 also handled).
//
// ROUND 7:
//  * attn: sched_barrier(0) after prefetch-issue forces a REAL 2-deep
//    register double buffer (round-6's VGPR=80 proved the compiler sank
//    the loads and defeated it).
//  * attn: K rows loaded sigma-permuted (sig(col)=8*(col>>2)+(col&3), and
//    sig+4 for the second QK mfma) so S^T lands as P[q=col][k=quad*8+j] —
//    the exact A-fragment of mfma_f32_16x16x32_bf16. PV now 8 K=32 mfmas
//    per tile instead of 16 K=16. Vt back to plain [d][s] (no perm).
//  * s_setprio(1) around MFMA clusters (T5, +4-7% on attn per m191).
//  * 7 convert launches -> 1; Q+K GEMMs fused into one 1024-block launch.
// ---------------------------------------------------------------------------

typedef unsigned short ushort_t;
typedef __bf16 bf16_8 __attribute__((ext_vector_type(8)));
typedef float f32x4 __attribute__((ext_vector_type(4)));
typedef unsigned short ushort8 __attribute__((ext_vector_type(8)));
typedef short short8v __attribute__((ext_vector_type(8)));

#define SEQ  1024
#define EMB  1024
#define NBAT 8
#define NH   16
#define HD   64
#define MROW (NBAT * SEQ)   // 8192

__device__ __forceinline__ ushort_t cvt_bf16(float x) {
  unsigned u = __float_as_uint(x);
  u += 0x7FFFu + ((u >> 16) & 1u);          // round-nearest-even
  return (ushort_t)(u >> 16);
}
__device__ __forceinline__ float bf2f(ushort_t u) {
  return __uint_as_float(((unsigned)u) << 16);
}
__device__ __forceinline__ short f2bs(float x) {
  return __builtin_bit_cast(short, (__bf16)x);   // pairs fuse to v_cvt_pk_bf16_f32
}

// global->LDS direct copy, 16 B/lane. lds base must be wave-uniform; HW
// writes lane i at base + i*16.
__device__ __forceinline__ void async_copy16(const ushort_t* g, ushort_t* l) {
  __builtin_amdgcn_global_load_lds(
      (const __attribute__((address_space(1))) void*)g,
      (__attribute__((address_space(3))) void*)l, 16, 0, 0);
}

// ---------------------------------------------------------------------------
// dtype probe: bf16 view of Wq with many |x|>=4 elements => buffer is fp32.
// ---------------------------------------------------------------------------
__global__ void dtype_probe(const ushort_t* __restrict__ w, int* __restrict__ flag) {
  __shared__ int cnt;
  if (threadIdx.x == 0) cnt = 0;
  __syncthreads();
  int c = 0;
  for (int i = threadIdx.x; i < 4096; i += 256) {
    const int e = (w[i] >> 7) & 0xFF;
    if (e >= 129) ++c;
  }
  atomicAdd(&cnt, c);
  __syncthreads();
  if (threadIdx.x == 0) *flag = (cnt > 256) ? 1 : 0;   // 1 = fp32 buffers
}

__device__ __forceinline__ ushort8 load8(const void* base, size_t off, bool f32) {
  if (f32) {
    const float* p = (const float*)base + off;
    const f32x4 a = *(const f32x4*)p;
    const f32x4 b = *(const f32x4*)(p + 4);
    ushort8 r;
    r[0] = cvt_bf16(a[0]); r[1] = cvt_bf16(a[1]);
    r[2] = cvt_bf16(a[2]); r[3] = cvt_bf16(a[3]);
    r[4] = cvt_bf16(b[0]); r[5] = cvt_bf16(b[1]);
    r[6] = cvt_bf16(b[2]); r[7] = cvt_bf16(b[3]);
    return r;
  }
  return *(const ushort8*)((const ushort_t*)base + off);
}

// ---------------------------------------------------------------------------
// Fused convert: all 7 buffers in one launch. Block ranges (256 thr, 8/thr):
//   [0,4096) q | [4096,8192) k | [8192,12288) v | then 4x512 for weights.
// ---------------------------------------------------------------------------
__global__ __launch_bounds__(256)
void convert_all(const void* __restrict__ q, const void* __restrict__ k,
                 const void* __restrict__ v, const void* __restrict__ wq,
                 const void* __restrict__ wk, const void* __restrict__ wv,
                 const void* __restrict__ wo,
                 ushort_t* __restrict__ cq, ushort_t* __restrict__ ck,
                 ushort_t* __restrict__ cv, ushort_t* __restrict__ cwq,
                 ushort_t* __restrict__ cwk, ushort_t* __restrict__ cwv,
                 ushort_t* __restrict__ cwo, const int* __restrict__ flag) {
  const bool f32 = (*flag != 0);
  const int b = blockIdx.x;
  const void* src;
  ushort_t* dst;
  int boff;
  if (b < 12288) {
    const int t = b >> 12;
    boff = b & 4095;
    src = (t == 0) ? q : (t == 1) ? k : v;
    dst = (t == 0) ? cq : (t == 1) ? ck : cv;
  } else {
    const int t = (b - 12288) >> 9;
    boff = (b - 12288) & 511;
    src = (t == 0) ? wq : (t == 1) ? wk : (t == 2) ? wv : wo;
    dst = (t == 0) ? cwq : (t == 1) ? cwk : (t == 2) ? cwv : cwo;
  }
  const size_t i = (size_t)boff * 256 + threadIdx.x;
  *(ushort8*)(dst + i * 8) = load8(src, i * 8, f32);
}

// ---------------------------------------------------------------------------
// GEMM body (pure bf16 A/B): C[m][n] = sum_k A[m][k]*B[n][k] + bias[n]
// 128x128 tile, BK=32, 4 waves 2x2, 4x4 mfma 16x16x32/wave, async staging.
// scatter: out to Vt[n][h][d][s] (plain). final_out && f32: fp32 out.
// ---------------------------------------------------------------------------
__device__ __forceinline__ void gemm_body(
    const ushort_t* __restrict__ A, const ushort_t* __restrict__ B,
    const void* __restrict__ bias, void* __restrict__ Cout, bool f32, int bid,
    int scatter, int final_out) {
  __shared__ __align__(16) ushort_t As[128 * 32];
  __shared__ __align__(16) ushort_t Bs[128 * 32];
  const int tid  = threadIdx.x;
  const int lane = tid & 63;
  const int wave = tid >> 6;
  const int wm = wave & 1, wn = wave >> 1;
  const int col  = lane & 15;
  const int quad = lane >> 4;
  const int bm = (bid & 63) << 7;
  const int bn = (bid >> 6) << 7;

  const ushort_t* Ab = A + (size_t)bm * EMB;
  const ushort_t* Bb = B + (size_t)bn * EMB;

  float bvv[4];
#pragma unroll
  for (int nt = 0; nt < 4; ++nt) {
    const int i = bn + wn * 64 + nt * 16 + col;
    bvv[nt] = f32 ? ((const float*)bias)[i] : bf2f(((const ushort_t*)bias)[i]);
  }

  f32x4 acc[4][4] = {};

  for (int kb = 0; kb < EMB; kb += 32) {
#pragma unroll
    for (int j = 0; j < 2; ++j) {
      const int s   = j * 256 + tid;       // slot: row=s>>2, 8-elem chunk=s&3
      const int row = s >> 2;
      const int ch  = (s & 3) << 3;
      const int s0  = j * 256 + wave * 64; // wave-uniform LDS base slot
      async_copy16(Ab + (size_t)row * EMB + kb + ch, &As[s0 * 8]);
      async_copy16(Bb + (size_t)row * EMB + kb + ch, &Bs[s0 * 8]);
    }
    __syncthreads();   // drains vmcnt -> async LDS writes visible

    bf16_8 af[4], bfr[4];
#pragma unroll
    for (int mt = 0; mt < 4; ++mt)
      af[mt] = *(const bf16_8*)(As + (wm * 64 + mt * 16 + col) * 32 + quad * 8);
#pragma unroll
    for (int nt = 0; nt < 4; ++nt)
      bfr[nt] = *(const bf16_8*)(Bs + (wn * 64 + nt * 16 + col) * 32 + quad * 8);
#pragma unroll
    for (int mt = 0; mt < 4; ++mt)
#pragma unroll
      for (int nt = 0; nt < 4; ++nt)
        acc[mt][nt] = __builtin_amdgcn_mfma_f32_16x16x32_bf16(af[mt], bfr[nt],
                                                              acc[mt][nt], 0, 0, 0);
    __syncthreads();   // frag reads done before next staging overwrites LDS
  }

#pragma unroll
  for (int mt = 0; mt < 4; ++mt)
#pragma unroll
    for (int nt = 0; nt < 4; ++nt) {
      const int gcol = bn + wn * 64 + nt * 16 + col;
#pragma unroll
      for (int r = 0; r < 4; ++r) {
        const int grow = bm + wm * 64 + mt * 16 + quad * 4 + r;
        const float vv = acc[mt][nt][r] + bvv[nt];
        if (!scatter) {
          const size_t idx = (size_t)grow * EMB + gcol;
          if (final_out && f32) ((float*)Cout)[idx] = vv;
          else                  ((ushort_t*)Cout)[idx] = cvt_bf16(vv);
        } else {
          const int nn = grow >> 10, ss = grow & 1023;
          const int hh = gcol >> 6,  dd = gcol & 63;
          ((ushort_t*)Cout)[(size_t)((nn * NH + hh) * HD + dd) * SEQ + ss] =
              cvt_bf16(vv);
        }
      }
    }
}

// fused Q+K projection: blocks [0,512) -> Q, [512,1024) -> K
__global__ __launch_bounds__(256)
void gemm_qk(const ushort_t* __restrict__ cq, const ushort_t* __restrict__ ck,
             const ushort_t* __restrict__ cWq, const ushort_t* __restrict__ cWk,
             const void* __restrict__ bq, const void* __restrict__ bk,
             void* __restrict__ Qp, void* __restrict__ Kp,
             const int* __restrict__ flag) {
  const bool f32 = (*flag != 0);
  const int which = blockIdx.x >> 9;
  const int bid = blockIdx.x & 511;
  const ushort_t* A = which ? ck : cq;
  const ushort_t* B = which ? cWk : cWq;
  const void* bi    = which ? bk : bq;
  void* C           = which ? Kp : Qp;
  gemm_body(A, B, bi, C, f32, bid, 0, 0);
}

__global__ __launch_bounds__(256)
void gemm_one(const ushort_t* __restrict__ A, const ushort_t* __restrict__ B,
              const void* __restrict__ bias, void* __restrict__ Cout,
              const int* __restrict__ flag, int scatter, int final_out) {
  gemm_body(A, B, bias, Cout, (*flag != 0), blockIdx.x, scatter, final_out);
}

// ---------------------------------------------------------------------------
// FLEX GEMM (fallback, external-dtype A/B via runtime flag)
// ---------------------------------------------------------------------------
template <int MODE>
__global__ __launch_bounds__(256)
void gemm_flex(const void* __restrict__ A, const void* __restrict__ B,
               const void* __restrict__ bias, void* __restrict__ Cout,
               const int* __restrict__ flag, int a_ext, int final_out) {
  __shared__ __align__(16) ushort_t As[128 * 32];
  __shared__ __align__(16) ushort_t Bs[128 * 32];
  const bool f32  = (*flag != 0);
  const bool af32 = f32 && (a_ext != 0);
  const int tid  = threadIdx.x;
  const int lane = tid & 63;
  const int wave = tid >> 6;
  const int wm = wave & 1, wn = wave >> 1;
  const int col  = lane & 15;
  const int quad = lane >> 4;
  const int bm = (blockIdx.x & 63) << 7;
  const int bn = (blockIdx.x >> 6) << 7;

  f32x4 acc[4][4] = {};

  for (int kb = 0; kb < EMB; kb += 32) {
    ushort8 ra[2], rb[2];
#pragma unroll
    for (int j = 0; j < 2; ++j) {
      const int s   = j * 256 + tid;
      const int row = s >> 2;
      const int ch  = (s & 3) << 3;
      ra[j] = load8(A, (size_t)(bm + row) * EMB + kb + ch, af32);
      rb[j] = load8(B, (size_t)(bn + row) * EMB + kb + ch, f32);
    }
#pragma unroll
    for (int j = 0; j < 2; ++j) {
      const int s = j * 256 + tid;
      *(ushort8*)(As + s * 8) = ra[j];
      *(ushort8*)(Bs + s * 8) = rb[j];
    }
    __syncthreads();

    bf16_8 af[4], bfr[4];
#pragma unroll
    for (int mt = 0; mt < 4; ++mt)
      af[mt] = *(const bf16_8*)(As + (wm * 64 + mt * 16 + col) * 32 + quad * 8);
#pragma unroll
    for (int nt = 0; nt < 4; ++nt)
      bfr[nt] = *(const bf16_8*)(Bs + (wn * 64 + nt * 16 + col) * 32 + quad * 8);
#pragma unroll
    for (int mt = 0; mt < 4; ++mt)
#pragma unroll
      for (int nt = 0; nt < 4; ++nt)
        acc[mt][nt] = __builtin_amdgcn_mfma_f32_16x16x32_bf16(af[mt], bfr[nt],
                                                              acc[mt][nt], 0, 0, 0);
    __syncthreads();
  }

  float bvv[4];
#pragma unroll
  for (int nt = 0; nt < 4; ++nt) {
    const int i = bn + wn * 64 + nt * 16 + col;
    bvv[nt] = f32 ? ((const float*)bias)[i] : bf2f(((const ushort_t*)bias)[i]);
  }
#pragma unroll
  for (int mt = 0; mt < 4; ++mt)
#pragma unroll
    for (int nt = 0; nt < 4; ++nt) {
      const int gcol = bn + wn * 64 + nt * 16 + col;
#pragma unroll
      for (int r = 0; r < 4; ++r) {
        const int grow = bm + wm * 64 + mt * 16 + quad * 4 + r;
        const float vv = acc[mt][nt][r] + bvv[nt];
        if (MODE == 0) {
          const size_t idx = (size_t)grow * EMB + gcol;
          if (final_out && f32) ((float*)Cout)[idx] = vv;
          else                  ((ushort_t*)Cout)[idx] = cvt_bf16(vv);
        } else {
          const int nn = grow >> 10, ss = grow & 1023;
          const int hh = gcol >> 6,  dd = gcol & 63;
          ((ushort_t*)Cout)[(size_t)((nn * NH + hh) * HD + dd) * SEQ + ss] =
              cvt_bf16(vv);
        }
      }
    }
}

// ---------------------------------------------------------------------------
// Fused flash attention, LDS-free, register double-buffered (enforced).
// Each wave: 32 q-rows (2 groups of 16) of one (n,h). Grid = 1024 blocks.
//
// QK^T with sigma-permuted K rows: lane col loads K row sig(col) =
// 8*(col>>2)+(col&3) (and sig+4 for the 2nd mfma). Output: lane holds
// S[k = kb + quad*8 + {0..3 from s0, 4..7 from s1}][q = q0 + col], i.e.
// pa = P[q=col][k=quad*8+j] is the exact A-fragment of the K=32 mfma.
// PV: acc[g][dt] = mfma_16x16x32(pa, V[kb+quad*8+j][dt*16+col], acc).
//
// sched_barrier(0) after each prefetch-issue pins the loads BEFORE the
// compute phase (round-6 VGPR=80 proved the compiler otherwise sinks them).
// Softmax: fixed offset, p = exp2(s*SCL - MOF); offset cancels exactly in
// the final normalization. Per-lane scalar row-sum (q = col).
// ---------------------------------------------------------------------------
__global__ __launch_bounds__(256)
void attn_kernel(const ushort_t* __restrict__ Q, const ushort_t* __restrict__ K,
                 const ushort_t* __restrict__ V, ushort_t* __restrict__ O) {
  const int tid  = threadIdx.x;
  const int lane = tid & 63;
  const int wave = tid >> 6;
  const int col  = lane & 15;
  const int quad = lane >> 4;
  const int gid = blockIdx.x;       // 1024 blocks
  const int nh  = gid & 127;
  const int qb  = gid >> 7;
  const int h  = nh & 15;
  const int n  = nh >> 4;
  const int q0 = qb * 128 + wave * 32;

  // Q fragments for 2 q-groups (rows q0+g*16+col), d 0..31 / 32..63
  bf16_8 aq0[2], aq1[2];
#pragma unroll
  for (int g = 0; g < 2; ++g) {
    const ushort_t* qp =
        Q + (size_t)(n * SEQ + q0 + g * 16 + col) * EMB + h * HD + quad * 8;
    aq0[g] = *(const bf16_8*)qp;
    aq1[g] = *(const bf16_8*)(qp + 32);
  }

  const int sig = ((col >> 2) << 3) | (col & 3);   // sigma(col)
  const ushort_t* kp = K + (size_t)(n * SEQ + sig) * EMB + h * HD + quad * 8;
  const ushort_t* vp = V + ((size_t)nh * HD + col) * SEQ + quad * 8;

  f32x4 acc[2][4] = {};
  float lsum[2] = {0.f, 0.f};

  const float SCL = 0.04508422f;    // log2(e)/sqrt(1024)
  const float MOF = 16.0f;          // fixed softmax offset (cancels exactly)

#define ATTN_LOAD(KX, VX, KB_)                                               \
  do {                                                                       \
    const ushort_t* kpi = kp + (size_t)(KB_) * EMB;                          \
    KX[0] = *(const bf16_8*)(kpi);                                           \
    KX[1] = *(const bf16_8*)(kpi + 32);                                      \
    KX[2] = *(const bf16_8*)(kpi + 4 * EMB);                                 \
    KX[3] = *(const bf16_8*)(kpi + 4 * EMB + 32);                            \
    _Pragma("unroll")                                                        \
    for (int dt = 0; dt < 4; ++dt)                                           \
      VX[dt] = *(const bf16_8*)(vp + (size_t)dt * 16 * SEQ + (KB_));         \
  } while (0)

#define ATTN_TILE(KX, VX)                                                    \
  do {                                                                       \
    _Pragma("unroll")                                                        \
    for (int g = 0; g < 2; ++g) {                                            \
      const f32x4 z = {};                                                    \
      __builtin_amdgcn_s_setprio(1);                                         \
      f32x4 s0 = __builtin_amdgcn_mfma_f32_16x16x32_bf16(KX[0], aq0[g], z, 0, 0, 0); \
      s0 = __builtin_amdgcn_mfma_f32_16x16x32_bf16(KX[1], aq1[g], s0, 0, 0, 0);      \
      f32x4 s1 = __builtin_amdgcn_mfma_f32_16x16x32_bf16(KX[2], aq0[g], z, 0, 0, 0); \
      s1 = __builtin_amdgcn_mfma_f32_16x16x32_bf16(KX[3], aq1[g], s1, 0, 0, 0);      \
      __builtin_amdgcn_s_setprio(0);                                         \
      short8v pas;                                                           \
      _Pragma("unroll")                                                      \
      for (int r = 0; r < 4; ++r) {                                          \
        const float p0 = exp2f(__builtin_fmaf(s0[r], SCL, -MOF));            \
        const float p1 = exp2f(__builtin_fmaf(s1[r], SCL, -MOF));            \
        lsum[g] += p0 + p1;                                                  \
        pas[r]     = f2bs(p0);                                               \
        pas[r + 4] = f2bs(p1);                                               \
      }                                                                      \
      const bf16_8 pab = __builtin_bit_cast(bf16_8, pas);                    \
      __builtin_amdgcn_s_setprio(1);                                         \
      _Pragma("unroll")                                                      \
      for (int dt = 0; dt < 4; ++dt)                                         \
        acc[g][dt] = __builtin_amdgcn_mfma_f32_16x16x32_bf16(pab, VX[dt], acc[g][dt], 0, 0, 0); \
      __builtin_amdgcn_s_setprio(0);                                         \
    }                                                                        \
  } while (0)

  bf16_8 KA[4], KB2[4], VA[4], VB[4];

  ATTN_LOAD(KA, VA, 0);
  for (int kb = 0; kb < SEQ; kb += 64) {
    ATTN_LOAD(KB2, VB, kb + 32);          // prefetch tile t+1
    __builtin_amdgcn_sched_barrier(0);    // pin loads BEFORE compute
    ATTN_TILE(KA, VA);
    if (kb + 64 < SEQ) {
      ATTN_LOAD(KA, VA, kb + 64);
      __builtin_amdgcn_sched_barrier(0);
    }
    ATTN_TILE(KB2, VB);
  }

#undef ATTN_LOAD
#undef ATTN_TILE

  // per-group row-sum reduction and output
#pragma unroll
  for (int g = 0; g < 2; ++g) {
    float tot = lsum[g];
    tot += __shfl_xor(tot, 16, 64);
    tot += __shfl_xor(tot, 32, 64);
    float rinv[4];
#pragma unroll
    for (int r = 0; r < 4; ++r)
      rinv[r] = 1.0f / __shfl(tot, quad * 4 + r, 16);
#pragma unroll
    for (int dt = 0; dt < 4; ++dt)
#pragma unroll
      for (int r = 0; r < 4; ++r)
        O[(size_t)(n * SEQ + q0 + g * 16 + quad * 4 + r) * EMB + h * HD +
          dt * 16 + col] = cvt_bf16(acc[g][dt][r] * rinv[r]);
  }
}

// ---------------------------------------------------------------------------
extern "C" void kernel_launch(void* const* d_in, const int* in_sizes, int n_in,
                              void* d_out, int out_size, void* d_ws, size_t ws_size,
                              hipStream_t stream) {
  const void* q  = d_in[0];
  const void* k  = d_in[1];
  const void* v  = d_in[2];
  const void* Wq = d_in[3];
  const void* bq = d_in[4];
  const void* Wk = d_in[5];
  const void* bk = d_in[6];
  const void* Wv = d_in[7];
  const void* bv = d_in[8];
  const void* Wo = d_in[9];
  const void* bo = d_in[10];

  const size_t TE = (size_t)MROW * EMB;   // 8.39M elems
  const size_t WE = (size_t)EMB * EMB;    // 1.05M elems
  int* flag = (int*)d_ws;
  char* base = (char*)d_ws + 256;
  const size_t NEED = 256 + (4 * TE + 4 * WE) * sizeof(ushort_t);

  const dim3 tB(256);
  dtype_probe<<<dim3(1), tB, 0, stream>>>((const ushort_t*)Wq, flag);

  if (ws_size >= NEED) {
    // fast path: convert everything to bf16 in one launch, fused Q+K GEMM
    ushort_t* cq  = (ushort_t*)base;            // becomes Vt after Q GEMM
    ushort_t* ck  = cq + TE;
    ushort_t* cv  = ck + TE;
    ushort_t* Qp  = cv + TE;                    // becomes O after attn
    ushort_t* cWq = Qp + TE;
    ushort_t* cWk = cWq + WE;
    ushort_t* cWv = cWk + WE;
    ushort_t* cWo = cWv + WE;
    ushort_t* Kp  = (ushort_t*)d_out;           // K staged in d_out (dead later)
    ushort_t* Vt  = cq;
    ushort_t* Oa  = Qp;

    convert_all<<<dim3(14336), tB, 0, stream>>>(q, k, v, Wq, Wk, Wv, Wo,
                                                cq, ck, cv, cWq, cWk, cWv, cWo,
                                                flag);

    gemm_qk<<<dim3(1024), tB, 0, stream>>>(cq, ck, cWq, cWk, bq, bk, Qp, Kp, flag);
    gemm_one<<<dim3(512), tB, 0, stream>>>(cv, cWv, bv, Vt, flag, 1, 0);  // cq dead
    attn_kernel<<<dim3(1024), tB, 0, stream>>>(Qp, Kp, Vt, Oa);
    gemm_one<<<dim3(512), tB, 0, stream>>>(Oa, cWo, bo, d_out, flag, 0, 1);
  } else {
    // fallback: on-the-fly dtype, register staging
    ushort_t* Qp = (ushort_t*)base;
    ushort_t* Vt = Qp + TE;
    ushort_t* Kp = (ushort_t*)d_out;
    ushort_t* Oa = Qp;
    const dim3 gB(512);
    gemm_flex<0><<<gB, tB, 0, stream>>>(q, Wq, bq, Qp, flag, 1, 0);
    gemm_flex<0><<<gB, tB, 0, stream>>>(k, Wk, bk, Kp, flag, 1, 0);
    gemm_flex<1><<<gB, tB, 0, stream>>>(v, Wv, bv, Vt, flag, 1, 0);
    attn_kernel<<<dim3(1024), tB, 0, stream>>>(Qp, Kp, Vt, Oa);
    gemm_flex<0><<<gB, tB, 0, stream>>>(Oa, Wo, bo, d_out, flag, 0, 1);
  }
}

// Round 4
// 332.428 us; speedup vs baseline: 1.8810x; 1.1980x over previous
//
#include <hip/hip_runtime.h>

// ---------------------------------------------------------------------------
// MultiHeadAttention: N=8, S=1024, E=1024, H=16, D=64. External buffers are
// fp32 (detected at runtime by dtype_probe; bf16 also handled).
//
// ROUND 8:
//  * attn: 64 q-rows per wave (G=4 groups) — same 8 K/V loads per k-tile now
//    amortize over 32 MFMAs (~540 cyc compute), covering L2 latency. Grid
//    512 blocks, fully resident, XCD pinning kept (nh % 8).
//  * V-GEMM operand swap: C[e][m] = sum_k Wv[e][k]*Xv[m][k] so the Vt[d][s]
//    epilogue writes contiguous 32B runs (was 2B stores at 2KB stride).
//  * Q+K+V GEMMs fused into ONE 1536-block launch (6 blocks/CU): Vt now in
//    d_out upper half (Kp lower half) so no alias hazard with cq.
//  * __builtin_amdgcn_exp2f for guaranteed single-instruction exp2.
// ---------------------------------------------------------------------------

typedef unsigned short ushort_t;
typedef __bf16 bf16_8 __attribute__((ext_vector_type(8)));
typedef float f32x4 __attribute__((ext_vector_type(4)));
typedef unsigned short ushort8 __attribute__((ext_vector_type(8)));
typedef short short8v __attribute__((ext_vector_type(8)));

#define SEQ  1024
#define EMB  1024
#define NBAT 8
#define NH   16
#define HD   64
#define MROW (NBAT * SEQ)   // 8192

__device__ __forceinline__ ushort_t cvt_bf16(float x) {
  unsigned u = __float_as_uint(x);
  u += 0x7FFFu + ((u >> 16) & 1u);          // round-nearest-even
  return (ushort_t)(u >> 16);
}
__device__ __forceinline__ float bf2f(ushort_t u) {
  return __uint_as_float(((unsigned)u) << 16);
}
__device__ __forceinline__ short f2bs(float x) {
  return __builtin_bit_cast(short, (__bf16)x);   // pairs fuse to v_cvt_pk_bf16_f32
}

// global->LDS direct copy, 16 B/lane. lds base must be wave-uniform; HW
// writes lane i at base + i*16.
__device__ __forceinline__ void async_copy16(const ushort_t* g, ushort_t* l) {
  __builtin_amdgcn_global_load_lds(
      (const __attribute__((address_space(1))) void*)g,
      (__attribute__((address_space(3))) void*)l, 16, 0, 0);
}

// ---------------------------------------------------------------------------
// dtype probe: bf16 view of Wq with many |x|>=4 elements => buffer is fp32.
// ---------------------------------------------------------------------------
__global__ void dtype_probe(const ushort_t* __restrict__ w, int* __restrict__ flag) {
  __shared__ int cnt;
  if (threadIdx.x == 0) cnt = 0;
  __syncthreads();
  int c = 0;
  for (int i = threadIdx.x; i < 4096; i += 256) {
    const int e = (w[i] >> 7) & 0xFF;
    if (e >= 129) ++c;
  }
  atomicAdd(&cnt, c);
  __syncthreads();
  if (threadIdx.x == 0) *flag = (cnt > 256) ? 1 : 0;   // 1 = fp32 buffers
}

__device__ __forceinline__ ushort8 load8(const void* base, size_t off, bool f32) {
  if (f32) {
    const float* p = (const float*)base + off;
    const f32x4 a = *(const f32x4*)p;
    const f32x4 b = *(const f32x4*)(p + 4);
    ushort8 r;
    r[0] = cvt_bf16(a[0]); r[1] = cvt_bf16(a[1]);
    r[2] = cvt_bf16(a[2]); r[3] = cvt_bf16(a[3]);
    r[4] = cvt_bf16(b[0]); r[5] = cvt_bf16(b[1]);
    r[6] = cvt_bf16(b[2]); r[7] = cvt_bf16(b[3]);
    return r;
  }
  return *(const ushort8*)((const ushort_t*)base + off);
}

// ---------------------------------------------------------------------------
// Fused convert: all 7 buffers in one launch. Block ranges (256 thr, 8/thr):
//   [0,4096) q | [4096,8192) k | [8192,12288) v | then 4x512 for weights.
// ---------------------------------------------------------------------------
__global__ __launch_bounds__(256)
void convert_all(const void* __restrict__ q, const void* __restrict__ k,
                 const void* __restrict__ v, const void* __restrict__ wq,
                 const void* __restrict__ wk, const void* __restrict__ wv,
                 const void* __restrict__ wo,
                 ushort_t* __restrict__ cq, ushort_t* __restrict__ ck,
                 ushort_t* __restrict__ cv, ushort_t* __restrict__ cwq,
                 ushort_t* __restrict__ cwk, ushort_t* __restrict__ cwv,
                 ushort_t* __restrict__ cwo, const int* __restrict__ flag) {
  const bool f32 = (*flag != 0);
  const int b = blockIdx.x;
  const void* src;
  ushort_t* dst;
  int boff;
  if (b < 12288) {
    const int t = b >> 12;
    boff = b & 4095;
    src = (t == 0) ? q : (t == 1) ? k : v;
    dst = (t == 0) ? cq : (t == 1) ? ck : cv;
  } else {
    const int t = (b - 12288) >> 9;
    boff = (b - 12288) & 511;
    src = (t == 0) ? wq : (t == 1) ? wk : (t == 2) ? wv : wo;
    dst = (t == 0) ? cwq : (t == 1) ? cwk : (t == 2) ? cwv : cwo;
  }
  const size_t i = (size_t)boff * 256 + threadIdx.x;
  *(ushort8*)(dst + i * 8) = load8(src, i * 8, f32);
}

// ---------------------------------------------------------------------------
// GEMM body (pure bf16 A/B): C[m][n] = sum_k A[m][k]*B[n][k] (+ bias)
// 128x128 tile, BK=32, 4 waves 2x2, 4x4 mfma 16x16x32/wave, async staging.
// mode 0: bf16 row-major out, bias[n].
// mode 1: swapped-V scatter — A=W rows e, B=X rows m; out Vt[n][h][d][s],
//         bias[e] (per-row). Writes are contiguous 32B runs along s.
// mode 2: final out — fp32 row-major if f32 else bf16, bias[n].
// LDS passed in (16 KB) so multi-branch callers share one allocation.
// ---------------------------------------------------------------------------
__device__ __forceinline__ void gemm_body(
    ushort_t* As, ushort_t* Bs,
    const ushort_t* __restrict__ A, const ushort_t* __restrict__ B,
    const void* __restrict__ bias, void* __restrict__ Cout, bool f32,
    int bm, int bn, int mode) {
  const int tid  = threadIdx.x;
  const int lane = tid & 63;
  const int wave = tid >> 6;
  const int wm = wave & 1, wn = wave >> 1;
  const int col  = lane & 15;
  const int quad = lane >> 4;

  const ushort_t* Ab = A + (size_t)bm * EMB;
  const ushort_t* Bb = B + (size_t)bn * EMB;

  float bvv[4];
  if (mode != 1) {
#pragma unroll
    for (int nt = 0; nt < 4; ++nt) {
      const int i = bn + wn * 64 + nt * 16 + col;
      bvv[nt] = f32 ? ((const float*)bias)[i] : bf2f(((const ushort_t*)bias)[i]);
    }
  }

  f32x4 acc[4][4] = {};

  for (int kb = 0; kb < EMB; kb += 32) {
#pragma unroll
    for (int j = 0; j < 2; ++j) {
      const int s   = j * 256 + tid;       // slot: row=s>>2, 8-elem chunk=s&3
      const int row = s >> 2;
      const int ch  = (s & 3) << 3;
      const int s0  = j * 256 + wave * 64; // wave-uniform LDS base slot
      async_copy16(Ab + (size_t)row * EMB + kb + ch, &As[s0 * 8]);
      async_copy16(Bb + (size_t)row * EMB + kb + ch, &Bs[s0 * 8]);
    }
    __syncthreads();   // drains vmcnt -> async LDS writes visible

    bf16_8 af[4], bfr[4];
#pragma unroll
    for (int mt = 0; mt < 4; ++mt)
      af[mt] = *(const bf16_8*)(As + (wm * 64 + mt * 16 + col) * 32 + quad * 8);
#pragma unroll
    for (int nt = 0; nt < 4; ++nt)
      bfr[nt] = *(const bf16_8*)(Bs + (wn * 64 + nt * 16 + col) * 32 + quad * 8);
#pragma unroll
    for (int mt = 0; mt < 4; ++mt)
#pragma unroll
      for (int nt = 0; nt < 4; ++nt)
        acc[mt][nt] = __builtin_amdgcn_mfma_f32_16x16x32_bf16(af[mt], bfr[nt],
                                                              acc[mt][nt], 0, 0, 0);
    __syncthreads();   // frag reads done before next staging overwrites LDS
  }

#pragma unroll
  for (int mt = 0; mt < 4; ++mt)
#pragma unroll
    for (int nt = 0; nt < 4; ++nt) {
      const int gcol = bn + wn * 64 + nt * 16 + col;
#pragma unroll
      for (int r = 0; r < 4; ++r) {
        const int grow = bm + wm * 64 + mt * 16 + quad * 4 + r;
        if (mode == 1) {
          const float bb =
              f32 ? ((const float*)bias)[grow] : bf2f(((const ushort_t*)bias)[grow]);
          const float vv = acc[mt][nt][r] + bb;
          const int nn = gcol >> 10, ss = gcol & 1023;
          const int hh = grow >> 6,  dd = grow & 63;
          ((ushort_t*)Cout)[(size_t)((nn * NH + hh) * HD + dd) * SEQ + ss] =
              cvt_bf16(vv);
        } else {
          const float vv = acc[mt][nt][r] + bvv[nt];
          const size_t idx = (size_t)grow * EMB + gcol;
          if (mode == 2 && f32) ((float*)Cout)[idx] = vv;
          else                  ((ushort_t*)Cout)[idx] = cvt_bf16(vv);
        }
      }
    }
}

// fused Q+K+V projections: [0,512) Q | [512,1024) K | [1024,1536) V-swapped
__global__ __launch_bounds__(256)
void gemm_qkv(const ushort_t* __restrict__ cq, const ushort_t* __restrict__ ck,
              const ushort_t* __restrict__ cv, const ushort_t* __restrict__ cWq,
              const ushort_t* __restrict__ cWk, const ushort_t* __restrict__ cWv,
              const void* __restrict__ bq, const void* __restrict__ bk,
              const void* __restrict__ bv, void* __restrict__ Qp,
              void* __restrict__ Kp, void* __restrict__ Vt,
              const int* __restrict__ flag) {
  __shared__ __align__(16) ushort_t As[128 * 32];
  __shared__ __align__(16) ushort_t Bs[128 * 32];
  const bool f32 = (*flag != 0);
  const int t = blockIdx.x >> 9;
  const int bid = blockIdx.x & 511;
  if (t == 0)
    gemm_body(As, Bs, cq, cWq, bq, Qp, f32, (bid & 63) << 7, (bid >> 6) << 7, 0);
  else if (t == 1)
    gemm_body(As, Bs, ck, cWk, bk, Kp, f32, (bid & 63) << 7, (bid >> 6) << 7, 0);
  else
    gemm_body(As, Bs, cWv, cv, bv, Vt, f32, (bid & 7) << 7, (bid >> 3) << 7, 1);
}

__global__ __launch_bounds__(256)
void gemm_one(const ushort_t* __restrict__ A, const ushort_t* __restrict__ B,
              const void* __restrict__ bias, void* __restrict__ Cout,
              const int* __restrict__ flag, int mode) {
  __shared__ __align__(16) ushort_t As[128 * 32];
  __shared__ __align__(16) ushort_t Bs[128 * 32];
  gemm_body(As, Bs, A, B, bias, Cout, (*flag != 0),
            (blockIdx.x & 63) << 7, (blockIdx.x >> 6) << 7, mode);
}

// ---------------------------------------------------------------------------
// FLEX GEMM (fallback, external-dtype A/B via runtime flag)
// ---------------------------------------------------------------------------
template <int MODE>
__global__ __launch_bounds__(256)
void gemm_flex(const void* __restrict__ A, const void* __restrict__ B,
               const void* __restrict__ bias, void* __restrict__ Cout,
               const int* __restrict__ flag, int a_ext, int final_out) {
  __shared__ __align__(16) ushort_t As[128 * 32];
  __shared__ __align__(16) ushort_t Bs[128 * 32];
  const bool f32  = (*flag != 0);
  const bool af32 = f32 && (a_ext != 0);
  const int tid  = threadIdx.x;
  const int lane = tid & 63;
  const int wave = tid >> 6;
  const int wm = wave & 1, wn = wave >> 1;
  const int col  = lane & 15;
  const int quad = lane >> 4;
  const int bm = (blockIdx.x & 63) << 7;
  const int bn = (blockIdx.x >> 6) << 7;

  f32x4 acc[4][4] = {};

  for (int kb = 0; kb < EMB; kb += 32) {
    ushort8 ra[2], rb[2];
#pragma unroll
    for (int j = 0; j < 2; ++j) {
      const int s   = j * 256 + tid;
      const int row = s >> 2;
      const int ch  = (s & 3) << 3;
      ra[j] = load8(A, (size_t)(bm + row) * EMB + kb + ch, af32);
      rb[j] = load8(B, (size_t)(bn + row) * EMB + kb + ch, f32);
    }
#pragma unroll
    for (int j = 0; j < 2; ++j) {
      const int s = j * 256 + tid;
      *(ushort8*)(As + s * 8) = ra[j];
      *(ushort8*)(Bs + s * 8) = rb[j];
    }
    __syncthreads();

    bf16_8 af[4], bfr[4];
#pragma unroll
    for (int mt = 0; mt < 4; ++mt)
      af[mt] = *(const bf16_8*)(As + (wm * 64 + mt * 16 + col) * 32 + quad * 8);
#pragma unroll
    for (int nt = 0; nt < 4; ++nt)
      bfr[nt] = *(const bf16_8*)(Bs + (wn * 64 + nt * 16 + col) * 32 + quad * 8);
#pragma unroll
    for (int mt = 0; mt < 4; ++mt)
#pragma unroll
      for (int nt = 0; nt < 4; ++nt)
        acc[mt][nt] = __builtin_amdgcn_mfma_f32_16x16x32_bf16(af[mt], bfr[nt],
                                                              acc[mt][nt], 0, 0, 0);
    __syncthreads();
  }

  float bvv[4];
#pragma unroll
  for (int nt = 0; nt < 4; ++nt) {
    const int i = bn + wn * 64 + nt * 16 + col;
    bvv[nt] = f32 ? ((const float*)bias)[i] : bf2f(((const ushort_t*)bias)[i]);
  }
#pragma unroll
  for (int mt = 0; mt < 4; ++mt)
#pragma unroll
    for (int nt = 0; nt < 4; ++nt) {
      const int gcol = bn + wn * 64 + nt * 16 + col;
#pragma unroll
      for (int r = 0; r < 4; ++r) {
        const int grow = bm + wm * 64 + mt * 16 + quad * 4 + r;
        const float vv = acc[mt][nt][r] + bvv[nt];
        if (MODE == 0) {
          const size_t idx = (size_t)grow * EMB + gcol;
          if (final_out && f32) ((float*)Cout)[idx] = vv;
          else                  ((ushort_t*)Cout)[idx] = cvt_bf16(vv);
        } else {
          const int nn = grow >> 10, ss = grow & 1023;
          const int hh = gcol >> 6,  dd = gcol & 63;
          ((ushort_t*)Cout)[(size_t)((nn * NH + hh) * HD + dd) * SEQ + ss] =
              cvt_bf16(vv);
        }
      }
    }
}

// ---------------------------------------------------------------------------
// Fused flash attention, LDS-free, register double-buffered, G=4.
// Each wave: 64 q-rows (4 groups of 16) of one (n,h). Grid = 512 blocks
// (4 waves x 64 rows = 256 rows/block, 4 blocks per (n,h)); all resident.
//
// QK^T with sigma-permuted K rows: lane col loads K row sig(col) =
// 8*(col>>2)+(col&3) (and sig+4 for the 2nd mfma). Output: lane holds
// S[k = kb + quad*8 + {0..3 from s0, 4..7 from s1}][q = q0 + col], i.e.
// pa = P[q=col][k=quad*8+j] is the exact A-fragment of the K=32 mfma.
// PV: acc[g][dt] = mfma_16x16x32(pa, V[kb+quad*8+j][dt*16+col], acc).
//
// sched_barrier(0) after each prefetch-issue pins the loads BEFORE the
// compute phase. Softmax: fixed offset, p = exp2(s*SCL - MOF); offset
// cancels exactly in the final normalization. Per-lane scalar row-sums.
// ---------------------------------------------------------------------------
__global__ __launch_bounds__(256)
void attn_kernel(const ushort_t* __restrict__ Q, const ushort_t* __restrict__ K,
                 const ushort_t* __restrict__ V, ushort_t* __restrict__ O) {
  const int tid  = threadIdx.x;
  const int lane = tid & 63;
  const int wave = tid >> 6;
  const int col  = lane & 15;
  const int quad = lane >> 4;
  const int gid = blockIdx.x;       // 512 blocks
  const int nh  = gid & 127;        // gid%8 = nh%8 -> XCD pinned per (n,h)
  const int qb  = gid >> 7;         // 0..3
  const int h  = nh & 15;
  const int n  = nh >> 4;
  const int q0 = qb * 256 + wave * 64;

  // Q fragments for 4 q-groups (rows q0+g*16+col), d 0..31 / 32..63
  bf16_8 aq0[4], aq1[4];
#pragma unroll
  for (int g = 0; g < 4; ++g) {
    const ushort_t* qp =
        Q + (size_t)(n * SEQ + q0 + g * 16 + col) * EMB + h * HD + quad * 8;
    aq0[g] = *(const bf16_8*)qp;
    aq1[g] = *(const bf16_8*)(qp + 32);
  }

  const int sig = ((col >> 2) << 3) | (col & 3);   // sigma(col)
  const ushort_t* kp = K + (size_t)(n * SEQ + sig) * EMB + h * HD + quad * 8;
  const ushort_t* vp = V + ((size_t)nh * HD + col) * SEQ + quad * 8;

  f32x4 acc[4][4] = {};
  float lsum[4] = {0.f, 0.f, 0.f, 0.f};

  const float SCL = 0.04508422f;    // log2(e)/sqrt(1024)
  const float MOF = 16.0f;          // fixed softmax offset (cancels exactly)

#define ATTN_LOAD(KX, VX, KB_)                                               \
  do {                                                                       \
    const ushort_t* kpi = kp + (size_t)(KB_) * EMB;                          \
    KX[0] = *(const bf16_8*)(kpi);                                           \
    KX[1] = *(const bf16_8*)(kpi + 32);                                      \
    KX[2] = *(const bf16_8*)(kpi + 4 * EMB);                                 \
    KX[3] = *(const bf16_8*)(kpi + 4 * EMB + 32);                            \
    _Pragma("unroll")                                                        \
    for (int dt = 0; dt < 4; ++dt)                                           \
      VX[dt] = *(const bf16_8*)(vp + (size_t)dt * 16 * SEQ + (KB_));         \
  } while (0)

#define ATTN_TILE(KX, VX)                                                    \
  do {                                                                       \
    _Pragma("unroll")                                                        \
    for (int g = 0; g < 4; ++g) {                                            \
      const f32x4 z = {};                                                    \
      __builtin_amdgcn_s_setprio(1);                                         \
      f32x4 s0 = __builtin_amdgcn_mfma_f32_16x16x32_bf16(KX[0], aq0[g], z, 0, 0, 0); \
      s0 = __builtin_amdgcn_mfma_f32_16x16x32_bf16(KX[1], aq1[g], s0, 0, 0, 0);      \
      f32x4 s1 = __builtin_amdgcn_mfma_f32_16x16x32_bf16(KX[2], aq0[g], z, 0, 0, 0); \
      s1 = __builtin_amdgcn_mfma_f32_16x16x32_bf16(KX[3], aq1[g], s1, 0, 0, 0);      \
      __builtin_amdgcn_s_setprio(0);                                         \
      short8v pas;                                                           \
      _Pragma("unroll")                                                      \
      for (int r = 0; r < 4; ++r) {                                          \
        const float p0 = __builtin_amdgcn_exp2f(__builtin_fmaf(s0[r], SCL, -MOF)); \
        const float p1 = __builtin_amdgcn_exp2f(__builtin_fmaf(s1[r], SCL, -MOF)); \
        lsum[g] += p0 + p1;                                                  \
        pas[r]     = f2bs(p0);                                               \
        pas[r + 4] = f2bs(p1);                                               \
      }                                                                      \
      const bf16_8 pab = __builtin_bit_cast(bf16_8, pas);                    \
      __builtin_amdgcn_s_setprio(1);                                         \
      _Pragma("unroll")                                                      \
      for (int dt = 0; dt < 4; ++dt)                                         \
        acc[g][dt] = __builtin_amdgcn_mfma_f32_16x16x32_bf16(pab, VX[dt], acc[g][dt], 0, 0, 0); \
      __builtin_amdgcn_s_setprio(0);                                         \
    }                                                                        \
  } while (0)

  bf16_8 KA[4], KB2[4], VA[4], VB[4];

  ATTN_LOAD(KA, VA, 0);
  for (int kb = 0; kb < SEQ; kb += 64) {
    ATTN_LOAD(KB2, VB, kb + 32);          // prefetch tile t+1
    __builtin_amdgcn_sched_barrier(0);    // pin loads BEFORE compute
    ATTN_TILE(KA, VA);
    if (kb + 64 < SEQ) {
      ATTN_LOAD(KA, VA, kb + 64);
      __builtin_amdgcn_sched_barrier(0);
    }
    ATTN_TILE(KB2, VB);
  }

#undef ATTN_LOAD
#undef ATTN_TILE

  // per-group row-sum reduction and output
#pragma unroll
  for (int g = 0; g < 4; ++g) {
    float tot = lsum[g];
    tot += __shfl_xor(tot, 16, 64);
    tot += __shfl_xor(tot, 32, 64);
    float rinv[4];
#pragma unroll
    for (int r = 0; r < 4; ++r)
      rinv[r] = 1.0f / __shfl(tot, quad * 4 + r, 16);
#pragma unroll
    for (int dt = 0; dt < 4; ++dt)
#pragma unroll
      for (int r = 0; r < 4; ++r)
        O[(size_t)(n * SEQ + q0 + g * 16 + quad * 4 + r) * EMB + h * HD +
          dt * 16 + col] = cvt_bf16(acc[g][dt][r] * rinv[r]);
  }
}

// ---------------------------------------------------------------------------
extern "C" void kernel_launch(void* const* d_in, const int* in_sizes, int n_in,
                              void* d_out, int out_size, void* d_ws, size_t ws_size,
                              hipStream_t stream) {
  const void* q  = d_in[0];
  const void* k  = d_in[1];
  const void* v  = d_in[2];
  const void* Wq = d_in[3];
  const void* bq = d_in[4];
  const void* Wk = d_in[5];
  const void* bk = d_in[6];
  const void* Wv = d_in[7];
  const void* bv = d_in[8];
  const void* Wo = d_in[9];
  const void* bo = d_in[10];

  const size_t TE = (size_t)MROW * EMB;   // 8.39M elems
  const size_t WE = (size_t)EMB * EMB;    // 1.05M elems
  int* flag = (int*)d_ws;
  char* base = (char*)d_ws + 256;
  const size_t NEED = 256 + (4 * TE + 4 * WE) * sizeof(ushort_t);

  const dim3 tB(256);
  dtype_probe<<<dim3(1), tB, 0, stream>>>((const ushort_t*)Wq, flag);

  if (ws_size >= NEED) {
    // fast path: convert all to bf16 in one launch, fused Q+K+V GEMM launch.
    // Kp in d_out lower half, Vt in d_out upper half (each 16.78 MB bf16);
    // both dead once the final O-GEMM overwrites d_out.
    ushort_t* cq  = (ushort_t*)base;
    ushort_t* ck  = cq + TE;
    ushort_t* cv  = ck + TE;
    ushort_t* Qp  = cv + TE;                    // becomes O after attn
    ushort_t* cWq = Qp + TE;
    ushort_t* cWk = cWq + WE;
    ushort_t* cWv = cWk + WE;
    ushort_t* cWo = cWv + WE;
    ushort_t* Kp  = (ushort_t*)d_out;
    ushort_t* Vt  = (ushort_t*)d_out + TE;
    ushort_t* Oa  = Qp;

    convert_all<<<dim3(14336), tB, 0, stream>>>(q, k, v, Wq, Wk, Wv, Wo,
                                                cq, ck, cv, cWq, cWk, cWv, cWo,
                                                flag);
    gemm_qkv<<<dim3(1536), tB, 0, stream>>>(cq, ck, cv, cWq, cWk, cWv,
                                            bq, bk, bv, Qp, Kp, Vt, flag);
    attn_kernel<<<dim3(512), tB, 0, stream>>>(Qp, Kp, Vt, Oa);
    gemm_one<<<dim3(512), tB, 0, stream>>>(Oa, cWo, bo, d_out, flag, 2);
  } else {
    // fallback: on-the-fly dtype, register staging
    ushort_t* Qp = (ushort_t*)base;
    ushort_t* Vt = Qp + TE;
    ushort_t* Kp = (ushort_t*)d_out;
    ushort_t* Oa = Qp;
    const dim3 gB(512);
    gemm_flex<0><<<gB, tB, 0, stream>>>(q, Wq, bq, Qp, flag, 1, 0);
    gemm_flex<0><<<gB, tB, 0, stream>>>(k, Wk, bk, Kp, flag, 1, 0);
    gemm_flex<1><<<gB, tB, 0, stream>>>(v, Wv, bv, Vt, flag, 1, 0);
    attn_kernel<<<dim3(512), tB, 0, stream>>>(Qp, Kp, Vt, Oa);
    gemm_flex<0><<<gB, tB, 0, stream>>>(Oa, Wo, bo, d_out, flag, 0, 1);
  }
}